// Round 11
// baseline (181.048 us; speedup 1.0000x reference)
//
#include <hip/hip_runtime.h>

#define BB 128
#define NN 1152
#define KD 512
#define NC 10
#define ND 16
#define CD 160   // NC*ND

typedef unsigned short ushort_t;
typedef unsigned int uint_t;
typedef short short8v __attribute__((ext_vector_type(8)));
typedef float float4v __attribute__((ext_vector_type(4)));
typedef float float16v __attribute__((ext_vector_type(16)));

__device__ __forceinline__ float bf2f(ushort_t u) {
  return __uint_as_float(((uint_t)u) << 16);
}
__device__ __forceinline__ ushort_t f2bf(float f) {
  uint_t x = __float_as_uint(f);
  x += 0x7fffu + ((x >> 16) & 1u);   // round-to-nearest-even
  return (ushort_t)(x >> 16);
}

// Barrier that does NOT drain vmcnt: LDS-visibility (lgkmcnt) only.
#define BAR_LDS() do {                                   \
    __builtin_amdgcn_sched_barrier(0);                   \
    asm volatile("s_waitcnt lgkmcnt(0)" ::: "memory");   \
    __builtin_amdgcn_s_barrier();                        \
    __builtin_amdgcn_sched_barrier(0);                   \
  } while (0)

// ---------- W transpose+convert: Wt[n][k] = bf16(W[k][n]), [160][512] ----------
__global__ __launch_bounds__(256) void wconv(const float* __restrict__ W,
                                             ushort_t* __restrict__ Wt) {
  int idx = blockIdx.x * 256 + threadIdx.x;   // 81920 total
  int n = idx >> 9, k = idx & 511;
  Wt[idx] = f2bf(W[(size_t)k * CD + n]);
}

// ---------- GEMM via 32x32x16 MFMA: BM=128, BK=32, 256 thr (4 waves) ----------
// r10 structure with BK halved -> LDS 36864 B -> 4 independent blocks/CU
// (16 waves/CU): barrier stalls of one block overlap streaming of others.
// 16 k-steps, ONE lgkmcnt-only barrier/step, vmcnt never drained, depth-2
// register prefetch. LDS rows 64B (4x16B slots); swizzle slot ^= (row>>1)&3
// (8 distinct 128B-positions per 16-lane group -> free 2-way).
// LDS: A[buf]@buf*8192 (128x32 bf16 8KB), B[buf]@16384+buf*10240 (10KB).
// Epilogue: Ct[64][168] @0 per 64-row half (2 passes) + sAf @32768.
__global__ __launch_bounds__(256, 4) void gemm_mfma(
    const float* __restrict__ x, const ushort_t* __restrict__ Wt,
    ushort_t* __restrict__ uhat, float* __restrict__ partials) {
  __shared__ __align__(16) char smem[36864];
  const int tid = threadIdx.x;
  const int wid = tid >> 6, lane = tid & 63;
  const int l31 = lane & 31, lh = lane >> 5;
  const int row0 = blockIdx.x * 128;

  float16v acc[5];
#pragma unroll
  for (int nt = 0; nt < 5; ++nt)
#pragma unroll
    for (int r = 0; r < 16; ++r) acc[nt][r] = 0.f;

  // A staging: 2 pieces u = tid + i*256 in [0,512): row = u>>2, hs = u&3
  int aby[2], arsrc[2];
#pragma unroll
  for (int i = 0; i < 2; ++i) {
    int u = tid + i * 256;
    int ar = u >> 2, hs = u & 3;
    arsrc[i] = ar * KD + hs * 8;                 // element offset (+k0)
    aby[i] = (ar << 6) + ((hs ^ ((ar >> 1) & 3)) << 4);
  }
  // B staging: 3 pieces f = tid + i*256 in [0,640): row = f>>2, s = f&3
  int bsrc[3], bby[3];
#pragma unroll
  for (int i = 0; i < 3; ++i) {
    int f = tid + i * 256;
    int br = (f >> 2) % 160, bs = f & 3;
    bsrc[i] = br * KD + bs * 8;
    bby[i] = (br << 6) + ((bs ^ ((br >> 1) & 3)) << 4);
  }
  const bool b2ok = tid < 128;                   // third piece mask (640-512)

  float4v rA[2][2];
  short8v rB[3];

  auto LOADS = [&](int ks) {
    int k0 = ks * 32;
#pragma unroll
    for (int i = 0; i < 2; ++i) {
      const float* p = x + (size_t)row0 * KD + arsrc[i] + k0;
      rA[i][0] = *reinterpret_cast<const float4v*>(p);
      rA[i][1] = *reinterpret_cast<const float4v*>(p + 4);
    }
    rB[0] = *reinterpret_cast<const short8v*>(Wt + bsrc[0] + k0);
    rB[1] = *reinterpret_cast<const short8v*>(Wt + bsrc[1] + k0);
    if (b2ok) rB[2] = *reinterpret_cast<const short8v*>(Wt + bsrc[2] + k0);
  };
  auto WRITES = [&](int buf) {
    char* Ab = smem + buf * 8192;
    char* Bb = smem + 16384 + buf * 10240;
#pragma unroll
    for (int i = 0; i < 2; ++i) {
      short8v pk;
#pragma unroll
      for (int e = 0; e < 4; ++e) {
        pk[e] = (short)f2bf(rA[i][0][e]);
        pk[e + 4] = (short)f2bf(rA[i][1][e]);
      }
      *reinterpret_cast<short8v*>(Ab + aby[i]) = pk;
    }
    *reinterpret_cast<short8v*>(Bb + bby[0]) = rB[0];
    *reinterpret_cast<short8v*>(Bb + bby[1]) = rB[1];
    if (b2ok) *reinterpret_cast<short8v*>(Bb + bby[2]) = rB[2];
  };

  const int arow = wid * 32 + l31;       // this lane's A row
  const int arx = (arow >> 1) & 3;
  LOADS(0);
  WRITES(0);
  LOADS(1);
  BAR_LDS();                             // tile 0 visible
  int cur = 0;
  for (int ks = 0; ks < 16; ++ks) {
    const char* Ab = smem + cur * 8192;
    const char* Bb = smem + 16384 + cur * 10240;
#pragma unroll
    for (int ss = 0; ss < 2; ++ss) {     // K=16 sub-steps of BK=32
      int slot = ss * 2 + lh;
      short8v a = *reinterpret_cast<const short8v*>(
          Ab + (arow << 6) + ((slot ^ arx) << 4));
#pragma unroll
      for (int nt = 0; nt < 5; ++nt) {
        int brow = nt * 32 + l31;
        short8v bfr = *reinterpret_cast<const short8v*>(
            Bb + (brow << 6) + ((slot ^ ((brow >> 1) & 3)) << 4));
        acc[nt] = __builtin_amdgcn_mfma_f32_32x32x16_bf16(a, bfr, acc[nt], 0, 0, 0);
      }
    }
    if (ks < 15) {
      WRITES(cur ^ 1);                   // tile ks+1 -> other buf
      if (ks < 14) LOADS(ks + 2);
    }
    BAR_LDS();
    cur ^= 1;
  }

  // ---- passA partials: col-sums over this block's 128 rows
  float* sAf = reinterpret_cast<float*>(smem + 32768);   // [4][160] = 2560 B
#pragma unroll
  for (int nt = 0; nt < 5; ++nt) {
    float p = 0.f;
#pragma unroll
    for (int r = 0; r < 16; ++r) p += acc[nt][r];
    p += __shfl_xor(p, 32);              // combine the two 16-row halves
    if (lh == 0) sAf[wid * CD + nt * 32 + l31] = p;
  }
  __syncthreads();
  if (tid < CD) {
    float s = sAf[tid] + sAf[CD + tid] + sAf[2 * CD + tid] + sAf[3 * CD + tid];
    partials[(size_t)blockIdx.x * CD + tid] = s;
  }

  // ---- C repack in two 64-row halves through Ct[64][168] (21504 B @0)
  ushort_t* Ct = reinterpret_cast<ushort_t*>(smem);
#pragma unroll
  for (int h = 0; h < 2; ++h) {
    if ((wid >> 1) == h) {
      int rbase = (wid & 1) * 32;
#pragma unroll
      for (int nt = 0; nt < 5; ++nt)
#pragma unroll
        for (int r = 0; r < 16; ++r) {
          int row = rbase + (r & 3) + 8 * (r >> 2) + 4 * lh;
          Ct[row * 168 + nt * 32 + l31] = f2bf(acc[nt][r]);
        }
    }
    __syncthreads();
#pragma unroll
    for (int i = 0; i < 5; ++i) {
      int p = tid + i * 256;             // 1280 pieces of 16B
      int row = p / 20, c0 = (p % 20) * 8;
      *reinterpret_cast<short8v*>(
          &uhat[(size_t)(row0 + h * 64 + row) * CD + c0]) =
          *reinterpret_cast<const short8v*>(&Ct[row * 168 + c0]);
    }
    if (h == 0) __syncthreads();
  }
}

// ---------- routing iteration with fused v-computation ----------
// vv = v0 = squash(0.1*sum(pg 9 chunks)); ITER2 adds v1 = squash(sum(p1)).
#define ITER_T 640
template <int ITER2>
__global__ __launch_bounds__(ITER_T) void iter_k(
    const ushort_t* __restrict__ uhat, const float* __restrict__ pg,
    const float* __restrict__ p1, float* __restrict__ pout) {
  __shared__ float bv[128][NC];        // 5120 B
  __shared__ float wv[128][NC];        // 5120 B
  __shared__ float sred[32][CD];       // 20480 B
  __shared__ float sred2[4][CD];       // 2560 B
  __shared__ float vv[CD];             // 640 B
  const int blk = blockIdx.x;
  const int b = blk / 9, ch = blk % 9;
  const int t = threadIdx.x;
  const int g = t / 20, q = t % 20;
  const int c = q >> 1;
  const ushort_t* ub = uhat + ((size_t)b * NN + ch * 128) * CD + q * 8;

  // ---- prologue: compute vv (= v0, or v0+v1 for ITER2)
  if (t < CD) {
    float s0 = 0.f;
#pragma unroll
    for (int cc = 0; cc < 9; ++cc) s0 += pg[((size_t)b * 9 + cc) * CD + t];
    s0 *= 0.1f;
    float ss = s0 * s0;
    ss += __shfl_xor(ss, 1); ss += __shfl_xor(ss, 2);
    ss += __shfl_xor(ss, 4); ss += __shfl_xor(ss, 8);
    float sn = sqrtf(ss) + 1e-7f;
    float v = s0 * sn / (1.f + sn * sn);
    if (ITER2) {
      float s1 = 0.f;
#pragma unroll
      for (int cc = 0; cc < 9; ++cc) s1 += p1[((size_t)b * 9 + cc) * CD + t];
      float ss1 = s1 * s1;
      ss1 += __shfl_xor(ss1, 1); ss1 += __shfl_xor(ss1, 2);
      ss1 += __shfl_xor(ss1, 4); ss1 += __shfl_xor(ss1, 8);
      float sn1 = sqrtf(ss1) + 1e-7f;
      v += s1 * sn1 / (1.f + sn1 * sn1);
    }
    vv[t] = v;
  }
  __syncthreads();

  float v0r[8];
  {
    float4v a = *reinterpret_cast<const float4v*>(&vv[q * 8]);
    float4v bb = *reinterpret_cast<const float4v*>(&vv[q * 8 + 4]);
#pragma unroll
    for (int e = 0; e < 4; ++e) { v0r[e] = a[e]; v0r[e + 4] = bb[e]; }
  }

  // ---- phase 1: logits
  short8v u8[4];
#pragma unroll
  for (int it = 0; it < 4; ++it) {
    int n = g + it * 32;
    u8[it] = *reinterpret_cast<const short8v*>(ub + (size_t)n * CD);
    float p = 0.f;
#pragma unroll
    for (int e = 0; e < 8; ++e) p += bf2f((ushort_t)u8[it][e]) * v0r[e];
    p += __shfl_xor(p, 1);
    if ((q & 1) == 0) bv[n][c] = p;
  }
  __syncthreads();

  // ---- phase 1.5: softmax weights once per row
  if (t < 128) {
    float e[NC];
    float bm = bv[t][0];
#pragma unroll
    for (int cc = 1; cc < NC; ++cc) bm = fmaxf(bm, bv[t][cc]);
    float Z = 0.f;
#pragma unroll
    for (int cc = 0; cc < NC; ++cc) { e[cc] = __expf(bv[t][cc] - bm); Z += e[cc]; }
    float rz = 1.f / Z;
#pragma unroll
    for (int cc = 0; cc < NC; ++cc) wv[t][cc] = e[cc] * rz;
  }
  __syncthreads();

  // ---- phase 2: weighted accumulate
  float a[8];
#pragma unroll
  for (int e = 0; e < 8; ++e) a[e] = 0.f;
#pragma unroll
  for (int it = 0; it < 4; ++it) {
    int n = g + it * 32;
    float w = wv[n][c];
#pragma unroll
    for (int e = 0; e < 8; ++e) a[e] += w * bf2f((ushort_t)u8[it][e]);
  }
  {
    float4v lo, hi;
#pragma unroll
    for (int e = 0; e < 4; ++e) { lo[e] = a[e]; hi[e] = a[e + 4]; }
    float4v* dst = reinterpret_cast<float4v*>(&sred[g][q * 8]);
    dst[0] = lo; dst[1] = hi;
  }
  __syncthreads();
  {
    int col = t % CD, part = t / CD;    // 640 = 4 x 160
    float s = 0.f;
#pragma unroll
    for (int g8 = 0; g8 < 8; ++g8) s += sred[part * 8 + g8][col];
    sred2[part][col] = s;
  }
  __syncthreads();
  if (t < CD) {
    pout[(size_t)blk * CD + t] =
        sred2[0][t] + sred2[1][t] + sred2[2][t] + sred2[3][t];
  }
}

// ---------- final squash ----------
__global__ __launch_bounds__(CD) void squash_out(
    const float* __restrict__ p2, float* __restrict__ outp) {
  int b = blockIdx.x, t = threadIdx.x;
  float s = 0.f;
#pragma unroll
  for (int cc = 0; cc < 9; ++cc) s += p2[((size_t)b * 9 + cc) * CD + t];
  float ss = s * s;
  ss += __shfl_xor(ss, 1); ss += __shfl_xor(ss, 2);
  ss += __shfl_xor(ss, 4); ss += __shfl_xor(ss, 8);
  float sn = sqrtf(ss) + 1e-7f;
  outp[(size_t)b * CD + t] = s * sn / (1.f + sn * sn);
}

extern "C" void kernel_launch(void* const* d_in, const int* in_sizes, int n_in,
                              void* d_out, int out_size, void* d_ws, size_t ws_size,
                              hipStream_t stream) {
  const float* x = (const float*)d_in[0];   // [128,1152,512] f32
  const float* W = (const float*)d_in[1];   // [512,160] f32
  float* out = (float*)d_out;               // [128,10,16] f32

  char* ws = (char*)d_ws;
  ushort_t* uhat = (ushort_t*)ws;                          // 47,185,920 B
  ushort_t* Wt   = (ushort_t*)(ws + 47185920);             //    163,840 B
  float*    pg   = (float*)(ws + 47349760);                //    737,280 B  [1152][160]
  float*    p1   = (float*)(ws + 48087040);                //    737,280 B
  float*    p2   = (float*)(ws + 48824320);                //    737,280 B

  wconv<<<320, 256, 0, stream>>>(W, Wt);
  gemm_mfma<<<1152, 256, 0, stream>>>(x, Wt, uhat, pg);
  iter_k<0><<<1152, ITER_T, 0, stream>>>(uhat, pg, nullptr, p1);  // s1 partials
  iter_k<1><<<1152, ITER_T, 0, stream>>>(uhat, pg, p1, p2);       // s2 partials
  squash_out<<<BB, CD, 0, stream>>>(p2, out);                     // out = v2
}

// Round 12
// 123.812 us; speedup vs baseline: 1.4623x; 1.4623x over previous
//
#include <hip/hip_runtime.h>

#define BB 128
#define NN 1152
#define KD 512
#define NC 10
#define ND 16
#define CD 160   // NC*ND

typedef unsigned short ushort_t;
typedef unsigned int uint_t;
typedef short short8v __attribute__((ext_vector_type(8)));
typedef float float4v __attribute__((ext_vector_type(4)));
typedef float float16v __attribute__((ext_vector_type(16)));

__device__ __forceinline__ float bf2f(ushort_t u) {
  return __uint_as_float(((uint_t)u) << 16);
}
__device__ __forceinline__ ushort_t f2bf(float f) {
  uint_t x = __float_as_uint(f);
  x += 0x7fffu + ((x >> 16) & 1u);   // round-to-nearest-even
  return (ushort_t)(x >> 16);
}

// Barrier that does NOT drain vmcnt: LDS-visibility (lgkmcnt) only.
#define BAR_LDS() do {                                   \
    __builtin_amdgcn_sched_barrier(0);                   \
    asm volatile("s_waitcnt lgkmcnt(0)" ::: "memory");   \
    __builtin_amdgcn_s_barrier();                        \
    __builtin_amdgcn_sched_barrier(0);                   \
  } while (0)

// ---------- W transpose+convert: Wt[n][k] = bf16(W[k][n]), [160][512] ----------
__global__ __launch_bounds__(256) void wconv(const float* __restrict__ W,
                                             ushort_t* __restrict__ Wt) {
  int idx = blockIdx.x * 256 + threadIdx.x;   // 81920 total
  int n = idx >> 9, k = idx & 511;
  Wt[idx] = f2bf(W[(size_t)k * CD + n]);
}

// ---------- GEMM 32x32x16: B LDS-dbuf, A DIRECT from global ----------
// r10 structure minus A staging. BM=128, BK=64, 256 thr = 4 waves; wave w =
// rows w*32..+32, all 160 cols (acc[5] f32x16). Grid 1152, 8 k-steps.
// A-frag: lane reads x[row0+w*32+l31][ks*64+ss*16+lh*8 ..+8) = 2 float4
// direct from global (rolling one-sub-step-ahead prefetch; 64B lines fully
// consumed across ss -> no extra HBM bytes, L1/L2 absorb fan-out).
// B: identical to r10 (dbuf LDS, depth-2 reg prefetch, swizzle slot^=(row&7),
// ONE lgkmcnt-only barrier per k-step, vmcnt never drained at barriers).
// LDS: B[buf] @ buf*20480 (40960 B); epilogue Ct[128][168] @0 (43008) +
// sAf @43008 (2560) -> 45568 B -> 3 blocks/CU.
__global__ __launch_bounds__(256, 2) void gemm_mfma(
    const float* __restrict__ x, const ushort_t* __restrict__ Wt,
    ushort_t* __restrict__ uhat, float* __restrict__ partials) {
  __shared__ __align__(16) char smem[45568];
  const int tid = threadIdx.x;
  const int wid = tid >> 6, lane = tid & 63;
  const int l31 = lane & 31, lh = lane >> 5;
  const int row0 = blockIdx.x * 128;

  float16v acc[5];
#pragma unroll
  for (int nt = 0; nt < 5; ++nt)
#pragma unroll
    for (int r = 0; r < 16; ++r) acc[nt][r] = 0.f;

  // B staging: 5 pieces f = tid + i*256 in [0,1280): row = f>>3 (0..159), slot = f&7
  int bsrc[5], bby[5];
#pragma unroll
  for (int i = 0; i < 5; ++i) {
    int f = tid + i * 256;
    int br = f >> 3, bs = f & 7;
    bsrc[i] = br * KD + bs * 8;
    bby[i] = (br << 7) + ((bs ^ (br & 7)) << 4);
  }
  short8v rB[5];

  auto LOADSB = [&](int ks) {
    int k0 = ks * 64;
#pragma unroll
    for (int i = 0; i < 5; ++i)
      rB[i] = *reinterpret_cast<const short8v*>(Wt + bsrc[i] + k0);
  };
  auto WRITESB = [&](int buf) {
    char* Bb = smem + buf * 20480;
#pragma unroll
    for (int i = 0; i < 5; ++i)
      *reinterpret_cast<short8v*>(Bb + bby[i]) = rB[i];
  };

  // A direct-load base: this lane's row, this lane-half's 8-float k slice
  const float* abase = x + (size_t)(row0 + wid * 32 + l31) * KD + lh * 8;

  LOADSB(0);
  WRITESB(0);
  LOADSB(1);
  float4v fa0 = *reinterpret_cast<const float4v*>(abase);
  float4v fa1 = *reinterpret_cast<const float4v*>(abase + 4);
  BAR_LDS();                             // B tile 0 visible
  int cur = 0;
  for (int ks = 0; ks < 8; ++ks) {
    const char* Bb = smem + cur * 20480;
#pragma unroll
    for (int ss = 0; ss < 4; ++ss) {     // K=16 sub-steps of BK=64
      // rolling prefetch of next sub-step's A frag (dummy reload at the end)
      int nks = ks, nss = ss + 1;
      if (nss == 4) { nss = 0; nks = (ks < 7) ? ks + 1 : 7; }
      const float* np = abase + nks * 64 + nss * 16;
      float4v nb0 = *reinterpret_cast<const float4v*>(np);
      float4v nb1 = *reinterpret_cast<const float4v*>(np + 4);
      short8v af;
#pragma unroll
      for (int e = 0; e < 4; ++e) {
        af[e] = (short)f2bf(fa0[e]);
        af[e + 4] = (short)f2bf(fa1[e]);
      }
      int slot = ss * 2 + lh;
#pragma unroll
      for (int nt = 0; nt < 5; ++nt) {
        int brow = nt * 32 + l31;
        short8v bfr = *reinterpret_cast<const short8v*>(
            Bb + (brow << 7) + ((slot ^ (brow & 7)) << 4));
        acc[nt] = __builtin_amdgcn_mfma_f32_32x32x16_bf16(af, bfr, acc[nt], 0, 0, 0);
      }
      fa0 = nb0; fa1 = nb1;
    }
    if (ks < 7) {
      WRITESB(cur ^ 1);                  // B tile ks+1 -> other buf
      if (ks < 6) LOADSB(ks + 2);
    }
    BAR_LDS();
    cur ^= 1;
  }

  // ---- passA partials: col-sums over this block's 128 rows
  float* sAf = reinterpret_cast<float*>(smem + 43008);   // [4][160] = 2560 B
#pragma unroll
  for (int nt = 0; nt < 5; ++nt) {
    float p = 0.f;
#pragma unroll
    for (int r = 0; r < 16; ++r) p += acc[nt][r];
    p += __shfl_xor(p, 32);              // combine the two 16-row halves
    if (lh == 0) sAf[wid * CD + nt * 32 + l31] = p;
  }

  // ---- C repack through LDS union -> coalesced 16B stores
  ushort_t* Ct = reinterpret_cast<ushort_t*>(smem);      // [128][168] = 43008 B
#pragma unroll
  for (int nt = 0; nt < 5; ++nt)
#pragma unroll
    for (int r = 0; r < 16; ++r) {
      int row = wid * 32 + (r & 3) + 8 * (r >> 2) + 4 * lh;
      Ct[row * 168 + nt * 32 + l31] = f2bf(acc[nt][r]);
    }
  __syncthreads();
  if (tid < CD) {
    float s = sAf[tid] + sAf[CD + tid] + sAf[2 * CD + tid] + sAf[3 * CD + tid];
    partials[(size_t)blockIdx.x * CD + tid] = s;
  }
#pragma unroll
  for (int i = 0; i < 10; ++i) {
    int p = tid + i * 256;               // 2560 pieces of 16B
    int row = p / 20, c0 = (p % 20) * 8;
    *reinterpret_cast<short8v*>(&uhat[(size_t)(row0 + row) * CD + c0]) =
        *reinterpret_cast<const short8v*>(&Ct[row * 168 + c0]);
  }
}

// ---------- routing iteration with fused v-computation ----------
// vv = v0 = squash(0.1*sum(pg 9 chunks)); ITER2 adds v1 = squash(sum(p1)).
#define ITER_T 640
template <int ITER2>
__global__ __launch_bounds__(ITER_T) void iter_k(
    const ushort_t* __restrict__ uhat, const float* __restrict__ pg,
    const float* __restrict__ p1, float* __restrict__ pout) {
  __shared__ float bv[128][NC];        // 5120 B
  __shared__ float wv[128][NC];        // 5120 B
  __shared__ float sred[32][CD];       // 20480 B
  __shared__ float sred2[4][CD];       // 2560 B
  __shared__ float vv[CD];             // 640 B
  const int blk = blockIdx.x;
  const int b = blk / 9, ch = blk % 9;
  const int t = threadIdx.x;
  const int g = t / 20, q = t % 20;
  const int c = q >> 1;
  const ushort_t* ub = uhat + ((size_t)b * NN + ch * 128) * CD + q * 8;

  // ---- prologue: compute vv (= v0, or v0+v1 for ITER2)
  if (t < CD) {
    float s0 = 0.f;
#pragma unroll
    for (int cc = 0; cc < 9; ++cc) s0 += pg[((size_t)b * 9 + cc) * CD + t];
    s0 *= 0.1f;
    float ss = s0 * s0;
    ss += __shfl_xor(ss, 1); ss += __shfl_xor(ss, 2);
    ss += __shfl_xor(ss, 4); ss += __shfl_xor(ss, 8);
    float sn = sqrtf(ss) + 1e-7f;
    float v = s0 * sn / (1.f + sn * sn);
    if (ITER2) {
      float s1 = 0.f;
#pragma unroll
      for (int cc = 0; cc < 9; ++cc) s1 += p1[((size_t)b * 9 + cc) * CD + t];
      float ss1 = s1 * s1;
      ss1 += __shfl_xor(ss1, 1); ss1 += __shfl_xor(ss1, 2);
      ss1 += __shfl_xor(ss1, 4); ss1 += __shfl_xor(ss1, 8);
      float sn1 = sqrtf(ss1) + 1e-7f;
      v += s1 * sn1 / (1.f + sn1 * sn1);
    }
    vv[t] = v;
  }
  __syncthreads();

  float v0r[8];
  {
    float4v a = *reinterpret_cast<const float4v*>(&vv[q * 8]);
    float4v bb = *reinterpret_cast<const float4v*>(&vv[q * 8 + 4]);
#pragma unroll
    for (int e = 0; e < 4; ++e) { v0r[e] = a[e]; v0r[e + 4] = bb[e]; }
  }

  // ---- phase 1: logits
  short8v u8[4];
#pragma unroll
  for (int it = 0; it < 4; ++it) {
    int n = g + it * 32;
    u8[it] = *reinterpret_cast<const short8v*>(ub + (size_t)n * CD);
    float p = 0.f;
#pragma unroll
    for (int e = 0; e < 8; ++e) p += bf2f((ushort_t)u8[it][e]) * v0r[e];
    p += __shfl_xor(p, 1);
    if ((q & 1) == 0) bv[n][c] = p;
  }
  __syncthreads();

  // ---- phase 1.5: softmax weights once per row
  if (t < 128) {
    float e[NC];
    float bm = bv[t][0];
#pragma unroll
    for (int cc = 1; cc < NC; ++cc) bm = fmaxf(bm, bv[t][cc]);
    float Z = 0.f;
#pragma unroll
    for (int cc = 0; cc < NC; ++cc) { e[cc] = __expf(bv[t][cc] - bm); Z += e[cc]; }
    float rz = 1.f / Z;
#pragma unroll
    for (int cc = 0; cc < NC; ++cc) wv[t][cc] = e[cc] * rz;
  }
  __syncthreads();

  // ---- phase 2: weighted accumulate
  float a[8];
#pragma unroll
  for (int e = 0; e < 8; ++e) a[e] = 0.f;
#pragma unroll
  for (int it = 0; it < 4; ++it) {
    int n = g + it * 32;
    float w = wv[n][c];
#pragma unroll
    for (int e = 0; e < 8; ++e) a[e] += w * bf2f((ushort_t)u8[it][e]);
  }
  {
    float4v lo, hi;
#pragma unroll
    for (int e = 0; e < 4; ++e) { lo[e] = a[e]; hi[e] = a[e + 4]; }
    float4v* dst = reinterpret_cast<float4v*>(&sred[g][q * 8]);
    dst[0] = lo; dst[1] = hi;
  }
  __syncthreads();
  {
    int col = t % CD, part = t / CD;    // 640 = 4 x 160
    float s = 0.f;
#pragma unroll
    for (int g8 = 0; g8 < 8; ++g8) s += sred[part * 8 + g8][col];
    sred2[part][col] = s;
  }
  __syncthreads();
  if (t < CD) {
    pout[(size_t)blk * CD + t] =
        sred2[0][t] + sred2[1][t] + sred2[2][t] + sred2[3][t];
  }
}

// ---------- final squash ----------
__global__ __launch_bounds__(CD) void squash_out(
    const float* __restrict__ p2, float* __restrict__ outp) {
  int b = blockIdx.x, t = threadIdx.x;
  float s = 0.f;
#pragma unroll
  for (int cc = 0; cc < 9; ++cc) s += p2[((size_t)b * 9 + cc) * CD + t];
  float ss = s * s;
  ss += __shfl_xor(ss, 1); ss += __shfl_xor(ss, 2);
  ss += __shfl_xor(ss, 4); ss += __shfl_xor(ss, 8);
  float sn = sqrtf(ss) + 1e-7f;
  outp[(size_t)b * CD + t] = s * sn / (1.f + sn * sn);
}

extern "C" void kernel_launch(void* const* d_in, const int* in_sizes, int n_in,
                              void* d_out, int out_size, void* d_ws, size_t ws_size,
                              hipStream_t stream) {
  const float* x = (const float*)d_in[0];   // [128,1152,512] f32
  const float* W = (const float*)d_in[1];   // [512,160] f32
  float* out = (float*)d_out;               // [128,10,16] f32

  char* ws = (char*)d_ws;
  ushort_t* uhat = (ushort_t*)ws;                          // 47,185,920 B
  ushort_t* Wt   = (ushort_t*)(ws + 47185920);             //    163,840 B
  float*    pg   = (float*)(ws + 47349760);                //    737,280 B  [1152][160]
  float*    p1   = (float*)(ws + 48087040);                //    737,280 B
  float*    p2   = (float*)(ws + 48824320);                //    737,280 B

  wconv<<<320, 256, 0, stream>>>(W, Wt);
  gemm_mfma<<<1152, 256, 0, stream>>>(x, Wt, uhat, pg);
  iter_k<0><<<1152, ITER_T, 0, stream>>>(uhat, pg, nullptr, p1);  // s1 partials
  iter_k<1><<<1152, ITER_T, 0, stream>>>(uhat, pg, p1, p2);       // s2 partials
  squash_out<<<BB, CD, 0, stream>>>(p2, out);                     // out = v2
}

// Round 13
// 105.834 us; speedup vs baseline: 1.7107x; 1.1699x over previous
//
#include <hip/hip_runtime.h>
#include <hip/hip_bf16.h>

#define BB 128
#define NN 1152
#define KD 512
#define NC 10
#define ND 16
#define CD 160   // NC*ND

typedef unsigned short ushort_t;
typedef unsigned int uint_t;
typedef short short8v __attribute__((ext_vector_type(8)));
typedef float float4v __attribute__((ext_vector_type(4)));
typedef float float16v __attribute__((ext_vector_type(16)));
typedef uint_t uint4v __attribute__((ext_vector_type(4)));

__device__ __forceinline__ float bf2f(ushort_t u) {
  return __uint_as_float(((uint_t)u) << 16);
}
// native RNE conversions (compiler emits v_cvt_pk_bf16_f32 / v_cvt)
__device__ __forceinline__ ushort_t f2bf(float f) {
  __hip_bfloat16 h = __float2bfloat16(f);
  union { __hip_bfloat16 h; ushort_t u; } cv; cv.h = h; return cv.u;
}
__device__ __forceinline__ uint_t pk2(float a, float b) {
  float2 f; f.x = a; f.y = b;
  __hip_bfloat162 h = __float22bfloat162_rn(f);
  union { __hip_bfloat162 h; uint_t u; } cv; cv.h = h; return cv.u;
}

#define SBAR() __builtin_amdgcn_sched_barrier(0)
#define GLOAD_LDS16(gp, lp)                                        \
  __builtin_amdgcn_global_load_lds(                                \
      (const __attribute__((address_space(1))) void*)(gp),         \
      (__attribute__((address_space(3))) void*)(lp), 16, 0, 0)

// ---------- W transpose+convert: Wt[n][k] = bf16(W[k][n]), [160][512] ----------
__global__ __launch_bounds__(256) void wconv(const float* __restrict__ W,
                                             ushort_t* __restrict__ Wt) {
  int idx = blockIdx.x * 256 + threadIdx.x;   // 81920 total
  int n = idx >> 9, k = idx & 511;
  Wt[idx] = f2bf(W[(size_t)k * CD + n]);
}

// ---------- GEMM 32x32x16: A reg-staged (cvt_pk), B via global_load_lds ----------
// r10 geometry: BM=128, BK=64, 256 thr = 4 waves; wave w = rows w*32..+32,
// all 160 cols (acc[5] f32x16). Grid 1152. 8 k-steps.
// B staging: global_load_lds width=16, LINEAR dest (HW: base+lane*16) with
// PRE-SWIZZLED per-lane global source (XOR involution) so the LDS image equals
// the swizzled layout [(row<<7) + ((slot^(row&7))<<4)] the reads expect.
// Barriers: counted s_waitcnt vmcnt(8) lgkmcnt(0) (keeps the 8 A-prefetch
// loads for ks+2 in flight; drains exactly the 5 B gload_lds of ks+1).
// LDS: A[buf]@buf*16384 (16KB), B[buf]@32768+buf*20480 (20KB), sAf@73728.
// Total 76288 -> 2 blocks/CU. Epilogue Ct[128][168]@0 union.
__global__ __launch_bounds__(256, 2) void gemm_mfma(
    const float* __restrict__ x, const ushort_t* __restrict__ Wt,
    ushort_t* __restrict__ uhat, float* __restrict__ partials) {
  __shared__ __align__(16) char smem[76288];
  const int tid = threadIdx.x;
  const int wid = tid >> 6, lane = tid & 63;
  const int l31 = lane & 31, lh = lane >> 5;
  const int row0 = blockIdx.x * 128;

  float16v acc[5];
#pragma unroll
  for (int nt = 0; nt < 5; ++nt)
#pragma unroll
    for (int r = 0; r < 16; ++r) acc[nt][r] = 0.f;

  // A staging: 4 pieces f = tid + i*256 in [0,1024): row = f>>3 (0..127), slot = f&7
  int aby[4];
#pragma unroll
  for (int i = 0; i < 4; ++i) {
    int f = tid + i * 256;
    int ar = f >> 3, s = f & 7;
    aby[i] = (ar << 7) + ((s ^ (ar & 7)) << 4);
  }
  const int arow_ = tid >> 3;            // row of piece 0 (rows advance 32/piece)
  const int akq = tid & 7;

  // B gload source coords: wave wid, instr j -> rows wid*40+j*8..+8
  const int brow_g = wid * 40 + (lane >> 3);       // +j*8 at issue
  const int bslot_g = lane & 7;                    // dest slot; src slot XOR'd per row

  float4v rA[4][2];

  auto LOADSA = [&](int ks) {
    int k0 = ks * 64;
#pragma unroll
    for (int i = 0; i < 4; ++i) {
      const float* p = x + (size_t)(row0 + arow_ + i * 32) * KD + k0 + akq * 8;
      rA[i][0] = *reinterpret_cast<const float4v*>(p);
      rA[i][1] = *reinterpret_cast<const float4v*>(p + 4);
    }
  };
  auto WRITESA = [&](int buf) {
    char* Ab = smem + buf * 16384;
#pragma unroll
    for (int i = 0; i < 4; ++i) {
      uint4v p;
      p[0] = pk2(rA[i][0][0], rA[i][0][1]);
      p[1] = pk2(rA[i][0][2], rA[i][0][3]);
      p[2] = pk2(rA[i][1][0], rA[i][1][1]);
      p[3] = pk2(rA[i][1][2], rA[i][1][3]);
      *reinterpret_cast<uint4v*>(Ab + aby[i]) = p;
    }
  };
  auto GLOADB = [&](int ks, int buf) {
    int k0 = ks * 64;
    char* lbase = smem + 32768 + buf * 20480 + wid * 5120;
#pragma unroll
    for (int j = 0; j < 5; ++j) {
      int row = brow_g + j * 8;
      int sslot = bslot_g ^ (row & 7);   // involution: pre-swizzled source
      const ushort_t* gp = Wt + row * KD + k0 + sslot * 8;
      GLOAD_LDS16(gp, lbase + j * 1024);
    }
  };

  const int arow = wid * 32 + l31;       // this lane's A row
  const int arx = arow & 7;

  LOADSA(0);
  WRITESA(0);
  GLOADB(0, 0);
  LOADSA(1);
  SBAR();
  asm volatile("s_waitcnt vmcnt(8) lgkmcnt(0)" ::: "memory");  // drain B0 only
  __builtin_amdgcn_s_barrier();
  SBAR();

  int cur = 0;
  for (int ks = 0; ks < 8; ++ks) {
    if (ks < 7) GLOADB(ks + 1, cur ^ 1);
    const char* Ab = smem + cur * 16384;
    const char* Bb = smem + 32768 + cur * 20480;
#pragma unroll
    for (int ss = 0; ss < 4; ++ss) {     // K=16 sub-steps of BK=64
      int slot = ss * 2 + lh;
      short8v a = *reinterpret_cast<const short8v*>(
          Ab + (arow << 7) + ((slot ^ arx) << 4));
#pragma unroll
      for (int nt = 0; nt < 5; ++nt) {
        int brow = nt * 32 + l31;
        short8v bfr = *reinterpret_cast<const short8v*>(
            Bb + (brow << 7) + ((slot ^ (brow & 7)) << 4));
        acc[nt] = __builtin_amdgcn_mfma_f32_32x32x16_bf16(a, bfr, acc[nt], 0, 0, 0);
      }
    }
    if (ks < 7) WRITESA(cur ^ 1);        // compiler waits A(ks+1) regs here
    if (ks < 6) LOADSA(ks + 2);          // 8 loads stay in flight across barrier
    SBAR();
    if (ks < 6)
      asm volatile("s_waitcnt vmcnt(8) lgkmcnt(0)" ::: "memory");
    else if (ks == 6)
      asm volatile("s_waitcnt vmcnt(0) lgkmcnt(0)" ::: "memory");
    else
      asm volatile("s_waitcnt lgkmcnt(0)" ::: "memory");
    __builtin_amdgcn_s_barrier();
    SBAR();
    cur ^= 1;
  }

  // ---- passA partials: col-sums over this block's 128 rows
  float* sAf = reinterpret_cast<float*>(smem + 73728);   // [4][160] = 2560 B
#pragma unroll
  for (int nt = 0; nt < 5; ++nt) {
    float p = 0.f;
#pragma unroll
    for (int r = 0; r < 16; ++r) p += acc[nt][r];
    p += __shfl_xor(p, 32);              // combine the two 16-row halves
    if (lh == 0) sAf[wid * CD + nt * 32 + l31] = p;
  }

  // ---- C repack through LDS union -> coalesced 16B stores
  ushort_t* Ct = reinterpret_cast<ushort_t*>(smem);      // [128][168] = 43008 B
#pragma unroll
  for (int nt = 0; nt < 5; ++nt)
#pragma unroll
    for (int r = 0; r < 16; ++r) {
      int row = wid * 32 + (r & 3) + 8 * (r >> 2) + 4 * lh;
      Ct[row * 168 + nt * 32 + l31] = f2bf(acc[nt][r]);
    }
  __syncthreads();
  if (tid < CD) {
    float s = sAf[tid] + sAf[CD + tid] + sAf[2 * CD + tid] + sAf[3 * CD + tid];
    partials[(size_t)blockIdx.x * CD + tid] = s;
  }
#pragma unroll
  for (int i = 0; i < 10; ++i) {
    int p = tid + i * 256;               // 2560 pieces of 16B
    int row = p / 20, c0 = (p % 20) * 8;
    *reinterpret_cast<short8v*>(&uhat[(size_t)(row0 + row) * CD + c0]) =
        *reinterpret_cast<const short8v*>(&Ct[row * 168 + c0]);
  }
}

// ---------- routing iteration with fused v-computation ----------
// vv = v0 = squash(0.1*sum(pg 9 chunks)); ITER2 adds v1 = squash(sum(p1)).
#define ITER_T 640
template <int ITER2>
__global__ __launch_bounds__(ITER_T) void iter_k(
    const ushort_t* __restrict__ uhat, const float* __restrict__ pg,
    const float* __restrict__ p1, float* __restrict__ pout) {
  __shared__ float bv[128][NC];        // 5120 B
  __shared__ float wv[128][NC];        // 5120 B
  __shared__ float sred[32][CD];       // 20480 B
  __shared__ float sred2[4][CD];       // 2560 B
  __shared__ float vv[CD];             // 640 B
  const int blk = blockIdx.x;
  const int b = blk / 9, ch = blk % 9;
  const int t = threadIdx.x;
  const int g = t / 20, q = t % 20;
  const int c = q >> 1;
  const ushort_t* ub = uhat + ((size_t)b * NN + ch * 128) * CD + q * 8;

  // ---- prologue: compute vv (= v0, or v0+v1 for ITER2)
  if (t < CD) {
    float s0 = 0.f;
#pragma unroll
    for (int cc = 0; cc < 9; ++cc) s0 += pg[((size_t)b * 9 + cc) * CD + t];
    s0 *= 0.1f;
    float ss = s0 * s0;
    ss += __shfl_xor(ss, 1); ss += __shfl_xor(ss, 2);
    ss += __shfl_xor(ss, 4); ss += __shfl_xor(ss, 8);
    float sn = sqrtf(ss) + 1e-7f;
    float v = s0 * sn / (1.f + sn * sn);
    if (ITER2) {
      float s1 = 0.f;
#pragma unroll
      for (int cc = 0; cc < 9; ++cc) s1 += p1[((size_t)b * 9 + cc) * CD + t];
      float ss1 = s1 * s1;
      ss1 += __shfl_xor(ss1, 1); ss1 += __shfl_xor(ss1, 2);
      ss1 += __shfl_xor(ss1, 4); ss1 += __shfl_xor(ss1, 8);
      float sn1 = sqrtf(ss1) + 1e-7f;
      v += s1 * sn1 / (1.f + sn1 * sn1);
    }
    vv[t] = v;
  }
  __syncthreads();

  float v0r[8];
  {
    float4v a = *reinterpret_cast<const float4v*>(&vv[q * 8]);
    float4v bb = *reinterpret_cast<const float4v*>(&vv[q * 8 + 4]);
#pragma unroll
    for (int e = 0; e < 4; ++e) { v0r[e] = a[e]; v0r[e + 4] = bb[e]; }
  }

  // ---- phase 1: logits
  short8v u8[4];
#pragma unroll
  for (int it = 0; it < 4; ++it) {
    int n = g + it * 32;
    u8[it] = *reinterpret_cast<const short8v*>(ub + (size_t)n * CD);
    float p = 0.f;
#pragma unroll
    for (int e = 0; e < 8; ++e) p += bf2f((ushort_t)u8[it][e]) * v0r[e];
    p += __shfl_xor(p, 1);
    if ((q & 1) == 0) bv[n][c] = p;
  }
  __syncthreads();

  // ---- phase 1.5: softmax weights once per row
  if (t < 128) {
    float e[NC];
    float bm = bv[t][0];
#pragma unroll
    for (int cc = 1; cc < NC; ++cc) bm = fmaxf(bm, bv[t][cc]);
    float Z = 0.f;
#pragma unroll
    for (int cc = 0; cc < NC; ++cc) { e[cc] = __expf(bv[t][cc] - bm); Z += e[cc]; }
    float rz = 1.f / Z;
#pragma unroll
    for (int cc = 0; cc < NC; ++cc) wv[t][cc] = e[cc] * rz;
  }
  __syncthreads();

  // ---- phase 2: weighted accumulate
  float a[8];
#pragma unroll
  for (int e = 0; e < 8; ++e) a[e] = 0.f;
#pragma unroll
  for (int it = 0; it < 4; ++it) {
    int n = g + it * 32;
    float w = wv[n][c];
#pragma unroll
    for (int e = 0; e < 8; ++e) a[e] += w * bf2f((ushort_t)u8[it][e]);
  }
  {
    float4v lo, hi;
#pragma unroll
    for (int e = 0; e < 4; ++e) { lo[e] = a[e]; hi[e] = a[e + 4]; }
    float4v* dst = reinterpret_cast<float4v*>(&sred[g][q * 8]);
    dst[0] = lo; dst[1] = hi;
  }
  __syncthreads();
  {
    int col = t % CD, part = t / CD;    // 640 = 4 x 160
    float s = 0.f;
#pragma unroll
    for (int g8 = 0; g8 < 8; ++g8) s += sred[part * 8 + g8][col];
    sred2[part][col] = s;
  }
  __syncthreads();
  if (t < CD) {
    pout[(size_t)blk * CD + t] =
        sred2[0][t] + sred2[1][t] + sred2[2][t] + sred2[3][t];
  }
}

// ---------- final squash ----------
__global__ __launch_bounds__(CD) void squash_out(
    const float* __restrict__ p2, float* __restrict__ outp) {
  int b = blockIdx.x, t = threadIdx.x;
  float s = 0.f;
#pragma unroll
  for (int cc = 0; cc < 9; ++cc) s += p2[((size_t)b * 9 + cc) * CD + t];
  float ss = s * s;
  ss += __shfl_xor(ss, 1); ss += __shfl_xor(ss, 2);
  ss += __shfl_xor(ss, 4); ss += __shfl_xor(ss, 8);
  float sn = sqrtf(ss) + 1e-7f;
  outp[(size_t)b * CD + t] = s * sn / (1.f + sn * sn);
}

extern "C" void kernel_launch(void* const* d_in, const int* in_sizes, int n_in,
                              void* d_out, int out_size, void* d_ws, size_t ws_size,
                              hipStream_t stream) {
  const float* x = (const float*)d_in[0];   // [128,1152,512] f32
  const float* W = (const float*)d_in[1];   // [512,160] f32
  float* out = (float*)d_out;               // [128,10,16] f32

  char* ws = (char*)d_ws;
  ushort_t* uhat = (ushort_t*)ws;                          // 47,185,920 B
  ushort_t* Wt   = (ushort_t*)(ws + 47185920);             //    163,840 B
  float*    pg   = (float*)(ws + 47349760);                //    737,280 B  [1152][160]
  float*    p1   = (float*)(ws + 48087040);                //    737,280 B
  float*    p2   = (float*)(ws + 48824320);                //    737,280 B

  wconv<<<320, 256, 0, stream>>>(W, Wt);
  gemm_mfma<<<1152, 256, 0, stream>>>(x, Wt, uhat, pg);
  iter_k<0><<<1152, ITER_T, 0, stream>>>(uhat, pg, nullptr, p1);  // s1 partials
  iter_k<1><<<1152, ITER_T, 0, stream>>>(uhat, pg, p1, p2);       // s2 partials
  squash_out<<<BB, CD, 0, stream>>>(p2, out);                     // out = v2
}

// Round 14
// 103.115 us; speedup vs baseline: 1.7558x; 1.0264x over previous
//
#include <hip/hip_runtime.h>
#include <hip/hip_bf16.h>

#define BB 128
#define NN 1152
#define KD 512
#define NC 10
#define ND 16
#define CD 160   // NC*ND

typedef unsigned short ushort_t;
typedef unsigned int uint_t;
typedef short short8v __attribute__((ext_vector_type(8)));
typedef float float4v __attribute__((ext_vector_type(4)));
typedef float float16v __attribute__((ext_vector_type(16)));
typedef uint_t uint4v __attribute__((ext_vector_type(4)));

__device__ __forceinline__ float bf2f(ushort_t u) {
  return __uint_as_float(((uint_t)u) << 16);
}
// native RNE conversions (compiler emits v_cvt_pk_bf16_f32 pairs)
__device__ __forceinline__ ushort_t f2bf(float f) {
  __hip_bfloat16 h = __float2bfloat16(f);
  union { __hip_bfloat16 h; ushort_t u; } cv; cv.h = h; return cv.u;
}
__device__ __forceinline__ uint_t pk2(float a, float b) {
  float2 f; f.x = a; f.y = b;
  __hip_bfloat162 h = __float22bfloat162_rn(f);
  union { __hip_bfloat162 h; uint_t u; } cv; cv.h = h; return cv.u;
}

// Barrier that does NOT drain vmcnt: LDS-visibility (lgkmcnt) only.
#define BAR_LDS() do {                                   \
    __builtin_amdgcn_sched_barrier(0);                   \
    asm volatile("s_waitcnt lgkmcnt(0)" ::: "memory");   \
    __builtin_amdgcn_s_barrier();                        \
    __builtin_amdgcn_sched_barrier(0);                   \
  } while (0)

// ---------- W transpose+convert: Wt[n][k] = bf16(W[k][n]), [160][512] ----------
__global__ __launch_bounds__(256) void wconv(const float* __restrict__ W,
                                             ushort_t* __restrict__ Wt) {
  int idx = blockIdx.x * 256 + threadIdx.x;   // 81920 total
  int n = idx >> 9, k = idx & 511;
  Wt[idx] = f2bf(W[(size_t)k * CD + n]);
}

// ---------- GEMM via 32x32x16 MFMA: BM=128, BK=64, 256 thr (4 waves) ----------
// r10 structure (best measured) + native cvt_pk staging + XCD block swizzle.
// Wave w = rows w*32..+32, all 160 cols (acc[5] f32x16). Grid 1152 = 8 XCD x 144.
// 8 k-steps, ONE lgkmcnt-only barrier/step, vmcnt never drained, depth-2
// register prefetch. Rows 128B, swizzle slot ^= (row&7).
// LDS: A[buf]@buf*16384 (16KB), B[buf]@32768+buf*20480 (20KB), sAf@43008.
// Total 73728 -> 2 blocks/CU. Epilogue Ct[128][168]@0 union.
__global__ __launch_bounds__(256, 2) void gemm_mfma(
    const float* __restrict__ x, const ushort_t* __restrict__ Wt,
    ushort_t* __restrict__ uhat, float* __restrict__ partials) {
  __shared__ __align__(16) char smem[73728];
  const int tid = threadIdx.x;
  const int wid = tid >> 6, lane = tid & 63;
  const int l31 = lane & 31, lh = lane >> 5;
  // XCD-aware bijective swizzle: 1152 = 8 * 144 (contiguous chunk per XCD)
  const int bid = blockIdx.x;
  const int swz = (bid & 7) * 144 + (bid >> 3);
  const int row0 = swz * 128;

  float16v acc[5];
#pragma unroll
  for (int nt = 0; nt < 5; ++nt)
#pragma unroll
    for (int r = 0; r < 16; ++r) acc[nt][r] = 0.f;

  // A staging: 4 pieces f = tid + i*256 in [0,1024): row = f>>3 (0..127), slot = f&7
  int aby[4];
#pragma unroll
  for (int i = 0; i < 4; ++i) {
    int f = tid + i * 256;
    int ar = f >> 3, s = f & 7;
    aby[i] = (ar << 7) + ((s ^ (ar & 7)) << 4);
  }
  const int arow_ = tid >> 3;            // row of piece 0 (rows advance by 32/piece)
  const int akq = tid & 7;
  // B staging: 5 pieces f = tid + i*256 in [0,1280): row = f>>3 (0..159), slot = f&7
  int bsrc[5], bby[5];
#pragma unroll
  for (int i = 0; i < 5; ++i) {
    int f = tid + i * 256;
    int br = f >> 3, bs = f & 7;
    bsrc[i] = br * KD + bs * 8;
    bby[i] = (br << 7) + ((bs ^ (br & 7)) << 4);
  }

  float4v rA[4][2];
  short8v rB[5];

  auto LOADS = [&](int ks) {
    int k0 = ks * 64;
#pragma unroll
    for (int i = 0; i < 4; ++i) {
      const float* p = x + (size_t)(row0 + arow_ + i * 32) * KD + k0 + akq * 8;
      rA[i][0] = *reinterpret_cast<const float4v*>(p);
      rA[i][1] = *reinterpret_cast<const float4v*>(p + 4);
    }
#pragma unroll
    for (int i = 0; i < 5; ++i)
      rB[i] = *reinterpret_cast<const short8v*>(Wt + bsrc[i] + k0);
  };
  auto WRITES = [&](int buf) {
    char* Ab = smem + buf * 16384;
    char* Bb = smem + 32768 + buf * 20480;
#pragma unroll
    for (int i = 0; i < 4; ++i) {
      uint4v p;
      p[0] = pk2(rA[i][0][0], rA[i][0][1]);
      p[1] = pk2(rA[i][0][2], rA[i][0][3]);
      p[2] = pk2(rA[i][1][0], rA[i][1][1]);
      p[3] = pk2(rA[i][1][2], rA[i][1][3]);
      *reinterpret_cast<uint4v*>(Ab + aby[i]) = p;
    }
#pragma unroll
    for (int i = 0; i < 5; ++i)
      *reinterpret_cast<short8v*>(Bb + bby[i]) = rB[i];
  };

  const int arow = wid * 32 + l31;       // this lane's A row
  const int arx = arow & 7;
  LOADS(0);
  WRITES(0);
  LOADS(1);
  BAR_LDS();                             // tile 0 visible
  int cur = 0;
  for (int ks = 0; ks < 8; ++ks) {
    const char* Ab = smem + cur * 16384;
    const char* Bb = smem + 32768 + cur * 20480;
#pragma unroll
    for (int ss = 0; ss < 4; ++ss) {     // K=16 sub-steps of BK=64
      int slot = ss * 2 + lh;
      short8v a = *reinterpret_cast<const short8v*>(
          Ab + (arow << 7) + ((slot ^ arx) << 4));
#pragma unroll
      for (int nt = 0; nt < 5; ++nt) {
        int brow = nt * 32 + l31;
        short8v bfr = *reinterpret_cast<const short8v*>(
            Bb + (brow << 7) + ((slot ^ (brow & 7)) << 4));
        acc[nt] = __builtin_amdgcn_mfma_f32_32x32x16_bf16(a, bfr, acc[nt], 0, 0, 0);
      }
    }
    if (ks < 7) {
      WRITES(cur ^ 1);                   // tile ks+1 -> other buf
      if (ks < 6) LOADS(ks + 2);
    }
    BAR_LDS();
    cur ^= 1;
  }

  // ---- passA partials: col-sums over this block's 128 rows
  float* sAf = reinterpret_cast<float*>(smem + 43008);   // [4][160] = 2560 B
#pragma unroll
  for (int nt = 0; nt < 5; ++nt) {
    float p = 0.f;
#pragma unroll
    for (int r = 0; r < 16; ++r) p += acc[nt][r];
    p += __shfl_xor(p, 32);              // combine the two 16-row halves
    if (lh == 0) sAf[wid * CD + nt * 32 + l31] = p;
  }

  // ---- C repack through LDS union -> coalesced 16B stores
  ushort_t* Ct = reinterpret_cast<ushort_t*>(smem);      // [128][168] = 43008 B
#pragma unroll
  for (int nt = 0; nt < 5; ++nt)
#pragma unroll
    for (int r = 0; r < 16; ++r) {
      int row = wid * 32 + (r & 3) + 8 * (r >> 2) + 4 * lh;
      Ct[row * 168 + nt * 32 + l31] = f2bf(acc[nt][r]);
    }
  __syncthreads();
  if (tid < CD) {
    float s = sAf[tid] + sAf[CD + tid] + sAf[2 * CD + tid] + sAf[3 * CD + tid];
    partials[(size_t)swz * CD + tid] = s;
  }
#pragma unroll
  for (int i = 0; i < 10; ++i) {
    int p = tid + i * 256;               // 2560 pieces of 16B
    int row = p / 20, c0 = (p % 20) * 8;
    *reinterpret_cast<short8v*>(&uhat[(size_t)(row0 + row) * CD + c0]) =
        *reinterpret_cast<const short8v*>(&Ct[row * 168 + c0]);
  }
}

// ---------- routing iteration with fused v-computation ----------
// vv = v0 = squash(0.1*sum(pg 9 chunks)); ITER2 adds v1 = squash(sum(p1)).
#define ITER_T 640
template <int ITER2>
__global__ __launch_bounds__(ITER_T) void iter_k(
    const ushort_t* __restrict__ uhat, const float* __restrict__ pg,
    const float* __restrict__ p1, float* __restrict__ pout) {
  __shared__ float bv[128][NC];        // 5120 B
  __shared__ float wv[128][NC];        // 5120 B
  __shared__ float sred[32][CD];       // 20480 B
  __shared__ float sred2[4][CD];       // 2560 B
  __shared__ float vv[CD];             // 640 B
  const int blk = blockIdx.x;
  const int b = blk / 9, ch = blk % 9;
  const int t = threadIdx.x;
  const int g = t / 20, q = t % 20;
  const int c = q >> 1;
  const ushort_t* ub = uhat + ((size_t)b * NN + ch * 128) * CD + q * 8;

  // ---- prologue: compute vv (= v0, or v0+v1 for ITER2)
  if (t < CD) {
    float s0 = 0.f;
#pragma unroll
    for (int cc = 0; cc < 9; ++cc) s0 += pg[((size_t)b * 9 + cc) * CD + t];
    s0 *= 0.1f;
    float ss = s0 * s0;
    ss += __shfl_xor(ss, 1); ss += __shfl_xor(ss, 2);
    ss += __shfl_xor(ss, 4); ss += __shfl_xor(ss, 8);
    float sn = sqrtf(ss) + 1e-7f;
    float v = s0 * sn / (1.f + sn * sn);
    if (ITER2) {
      float s1 = 0.f;
#pragma unroll
      for (int cc = 0; cc < 9; ++cc) s1 += p1[((size_t)b * 9 + cc) * CD + t];
      float ss1 = s1 * s1;
      ss1 += __shfl_xor(ss1, 1); ss1 += __shfl_xor(ss1, 2);
      ss1 += __shfl_xor(ss1, 4); ss1 += __shfl_xor(ss1, 8);
      float sn1 = sqrtf(ss1) + 1e-7f;
      v += s1 * sn1 / (1.f + sn1 * sn1);
    }
    vv[t] = v;
  }
  __syncthreads();

  float v0r[8];
  {
    float4v a = *reinterpret_cast<const float4v*>(&vv[q * 8]);
    float4v bb = *reinterpret_cast<const float4v*>(&vv[q * 8 + 4]);
#pragma unroll
    for (int e = 0; e < 4; ++e) { v0r[e] = a[e]; v0r[e + 4] = bb[e]; }
  }

  // ---- phase 1: logits
  short8v u8[4];
#pragma unroll
  for (int it = 0; it < 4; ++it) {
    int n = g + it * 32;
    u8[it] = *reinterpret_cast<const short8v*>(ub + (size_t)n * CD);
    float p = 0.f;
#pragma unroll
    for (int e = 0; e < 8; ++e) p += bf2f((ushort_t)u8[it][e]) * v0r[e];
    p += __shfl_xor(p, 1);
    if ((q & 1) == 0) bv[n][c] = p;
  }
  __syncthreads();

  // ---- phase 1.5: softmax weights once per row
  if (t < 128) {
    float e[NC];
    float bm = bv[t][0];
#pragma unroll
    for (int cc = 1; cc < NC; ++cc) bm = fmaxf(bm, bv[t][cc]);
    float Z = 0.f;
#pragma unroll
    for (int cc = 0; cc < NC; ++cc) { e[cc] = __expf(bv[t][cc] - bm); Z += e[cc]; }
    float rz = 1.f / Z;
#pragma unroll
    for (int cc = 0; cc < NC; ++cc) wv[t][cc] = e[cc] * rz;
  }
  __syncthreads();

  // ---- phase 2: weighted accumulate
  float a[8];
#pragma unroll
  for (int e = 0; e < 8; ++e) a[e] = 0.f;
#pragma unroll
  for (int it = 0; it < 4; ++it) {
    int n = g + it * 32;
    float w = wv[n][c];
#pragma unroll
    for (int e = 0; e < 8; ++e) a[e] += w * bf2f((ushort_t)u8[it][e]);
  }
  {
    float4v lo, hi;
#pragma unroll
    for (int e = 0; e < 4; ++e) { lo[e] = a[e]; hi[e] = a[e + 4]; }
    float4v* dst = reinterpret_cast<float4v*>(&sred[g][q * 8]);
    dst[0] = lo; dst[1] = hi;
  }
  __syncthreads();
  {
    int col = t % CD, part = t / CD;    // 640 = 4 x 160
    float s = 0.f;
#pragma unroll
    for (int g8 = 0; g8 < 8; ++g8) s += sred[part * 8 + g8][col];
    sred2[part][col] = s;
  }
  __syncthreads();
  if (t < CD) {
    pout[(size_t)blk * CD + t] =
        sred2[0][t] + sred2[1][t] + sred2[2][t] + sred2[3][t];
  }
}

// ---------- final squash ----------
__global__ __launch_bounds__(CD) void squash_out(
    const float* __restrict__ p2, float* __restrict__ outp) {
  int b = blockIdx.x, t = threadIdx.x;
  float s = 0.f;
#pragma unroll
  for (int cc = 0; cc < 9; ++cc) s += p2[((size_t)b * 9 + cc) * CD + t];
  float ss = s * s;
  ss += __shfl_xor(ss, 1); ss += __shfl_xor(ss, 2);
  ss += __shfl_xor(ss, 4); ss += __shfl_xor(ss, 8);
  float sn = sqrtf(ss) + 1e-7f;
  outp[(size_t)b * CD + t] = s * sn / (1.f + sn * sn);
}

extern "C" void kernel_launch(void* const* d_in, const int* in_sizes, int n_in,
                              void* d_out, int out_size, void* d_ws, size_t ws_size,
                              hipStream_t stream) {
  const float* x = (const float*)d_in[0];   // [128,1152,512] f32
  const float* W = (const float*)d_in[1];   // [512,160] f32
  float* out = (float*)d_out;               // [128,10,16] f32

  char* ws = (char*)d_ws;
  ushort_t* uhat = (ushort_t*)ws;                          // 47,185,920 B
  ushort_t* Wt   = (ushort_t*)(ws + 47185920);             //    163,840 B
  float*    pg   = (float*)(ws + 47349760);                //    737,280 B  [1152][160]
  float*    p1   = (float*)(ws + 48087040);                //    737,280 B
  float*    p2   = (float*)(ws + 48824320);                //    737,280 B

  wconv<<<320, 256, 0, stream>>>(W, Wt);
  gemm_mfma<<<1152, 256, 0, stream>>>(x, Wt, uhat, pg);
  iter_k<0><<<1152, ITER_T, 0, stream>>>(uhat, pg, nullptr, p1);  // s1 partials
  iter_k<1><<<1152, ITER_T, 0, stream>>>(uhat, pg, p1, p2);       // s2 partials
  squash_out<<<BB, CD, 0, stream>>>(p2, out);                     // out = v2
}